// Round 8
// baseline (338.109 us; speedup 1.0000x reference)
//
#include <hip/hip_runtime.h>

// Involution fused kernels for MI355X (gfx950).  DIAGNOSTIC ROUND:
// exact R5 structure, each kernel body repeated REPS=4x (idempotent,
// memory-clobber between reps) so per-kernel durations+counters rise
// above the harness's 40us ws-fill dispatches into rocprof's top-5.
// x: (4,256,56,56) f32, w1: (64,256), bn(64), w2: (784,64), b2: (784)
// out: (4,256,56,56) f32
// ws: ybf16 [4][3136][64] | wprep bf16 [16][64][64] | b2pad f32 [16][64] | w1T f32 [256][64]

#define HW    3136
#define WIDE  56
#define C_IN  256
#define CR    64
#define GC    16
#define KK    49
#define BN_EPS 1e-5f
#define REPS  4

typedef __attribute__((ext_vector_type(8))) short short8;
typedef __attribute__((ext_vector_type(4))) float f32x4;
typedef __attribute__((ext_vector_type(2))) unsigned int u32x2;

__device__ __forceinline__ unsigned short f2bf(float f) {
    unsigned u = __float_as_uint(f);
    return (unsigned short)((u + 0x7FFFu + ((u >> 16) & 1u)) >> 16);   // RNE
}

// ---- Prep: w1T[c][o] f32; wprep[g][k][c] bf16 (k>=49 zero); b2pad[g][k] f32 ----
__global__ __launch_bounds__(256) void prep_kernel(
    const float* __restrict__ w1, const float* __restrict__ w2,
    const float* __restrict__ b2,
    float* __restrict__ w1T, unsigned short* __restrict__ wprep,
    float* __restrict__ b2pad)
{
    const int t = blockIdx.x * 256 + threadIdx.x;   // 0..65535
    if (t < 16384) {                                // w1T: c=t>>6, o=t&63
        const int c = t >> 6, o = t & 63;
        w1T[c * 64 + o] = w1[o * C_IN + c];
    }
    {                                               // wprep: g=t>>12, k=(t>>6)&63, c=t&63
        const int g = t >> 12, k = (t >> 6) & 63, c = t & 63;
        wprep[t] = (k < KK) ? f2bf(w2[(size_t)(g * KK + k) * CR + c]) : (unsigned short)0;
    }
    if (t < 1024) {                                 // b2pad
        const int g = t >> 6, k = t & 63;
        b2pad[t] = (k < KK) ? b2[g * KK + k] : 0.f;
    }
}

// ---- Kernel 1: y = relu(bn(w1 @ x)) -> bf16, layout [b][px][c] ----
// grid (196 px-tiles, 4 og-quads) x 256 thr (exact R5 config), body x4.
__global__ __launch_bounds__(256) void conv1_bn_relu(
    const float* __restrict__ x, const float* __restrict__ w1T,
    const float* __restrict__ gamma, const float* __restrict__ beta,
    const float* __restrict__ mean, const float* __restrict__ var,
    unsigned short* __restrict__ ybf)
{
    const int t    = threadIdx.x;
    const int lane = t & 63;
    const int og   = __builtin_amdgcn_readfirstlane(blockIdx.y * 4 + (t >> 6)); // 0..15
    const int tile = blockIdx.x;          // 0..195
    const int b    = tile / 49;
    const int hw   = (tile - b * 49) * 64 + lane;

    for (int rep = 0; rep < REPS; ++rep) {
        const float* __restrict__ xb = x + (size_t)b * C_IN * HW + hw;

        float acc[4] = {0.f, 0.f, 0.f, 0.f};
#pragma unroll 8
        for (int c = 0; c < C_IN; ++c) {
            const float xv = xb[(size_t)c * HW];
            const f32x4 wv = *(const f32x4*)(w1T + c * 64 + og * 4);   // uniform -> s_load_dwordx4
#pragma unroll
            for (int u = 0; u < 4; ++u) acc[u] += wv[u] * xv;
        }

        unsigned short o4[4];
#pragma unroll
        for (int u = 0; u < 4; ++u) {
            const int o = og * 4 + u;
            const float sc = gamma[o] * rsqrtf(var[o] + BN_EPS);
            const float sh = beta[o] - mean[o] * sc;
            o4[u] = f2bf(fmaxf(acc[u] * sc + sh, 0.f));
        }
        u32x2 pack;
        pack.x = (unsigned)o4[0] | ((unsigned)o4[1] << 16);
        pack.y = (unsigned)o4[2] | ((unsigned)o4[3] << 16);
        *(u32x2*)(ybf + ((size_t)(b * HW + hw)) * 64 + og * 4) = pack;

        asm volatile("" ::: "memory");   // force full re-execution per rep
    }
}

// ---- Kernel 2: MFMA conv2 + vectorized involution (exact R5), body x4. ----
__global__ __launch_bounds__(64) void conv2_involution(
    const float* __restrict__ x, const unsigned short* __restrict__ ybf,
    const unsigned short* __restrict__ wprep, const float* __restrict__ b2pad,
    float* __restrict__ out)
{
    __shared__ float kw_lds[64 * 64];   // [tap][px], 16 KB

    const int tid  = threadIdx.x;
    const int l15  = tid & 15;
    const int lg   = tid >> 4;
    const int tile = blockIdx.x;                 // 0..48
    const int g    = blockIdx.y & 15;
    const int b    = blockIdx.y >> 4;

    for (int rep = 0; rep < REPS; ++rep) {

    // ---- Phase 1: kw = W2g @ y  (per-pixel 64-tap kernels) ----
    {
        short8 Bf[4][2], Af[4][2];
#pragma unroll
        for (int ct = 0; ct < 4; ++ct) {
            const int hwp = tile * 64 + ct * 16 + l15;
            const unsigned short* yb = ybf + ((size_t)(b * HW + hwp)) * 64 + lg * 8;
            Bf[ct][0] = *(const short8*)(yb);
            Bf[ct][1] = *(const short8*)(yb + 32);
        }
#pragma unroll
        for (int rt = 0; rt < 4; ++rt) {
            const unsigned short* ar = wprep + g * 4096 + (rt * 16 + l15) * 64 + lg * 8;
            Af[rt][0] = *(const short8*)(ar);
            Af[rt][1] = *(const short8*)(ar + 32);
        }
        f32x4 acc[4][4];
#pragma unroll
        for (int ct = 0; ct < 4; ++ct)
#pragma unroll
            for (int rt = 0; rt < 4; ++rt) {
                acc[ct][rt] = (f32x4){0.f, 0.f, 0.f, 0.f};
                acc[ct][rt] = __builtin_amdgcn_mfma_f32_16x16x32_bf16(Af[rt][0], Bf[ct][0], acc[ct][rt], 0, 0, 0);
                acc[ct][rt] = __builtin_amdgcn_mfma_f32_16x16x32_bf16(Af[rt][1], Bf[ct][1], acc[ct][rt], 0, 0, 0);
            }

        float bias[4][4];
#pragma unroll
        for (int rt = 0; rt < 4; ++rt)
#pragma unroll
            for (int r = 0; r < 4; ++r)
                bias[rt][r] = b2pad[g * 64 + rt * 16 + lg * 4 + r];

#pragma unroll
        for (int ct = 0; ct < 4; ++ct) {
            const int pxc = ct * 16 + l15;
            const int hwp = tile * 64 + pxc;
            const int hp  = hwp / WIDE;
            const int wp  = hwp - hp * WIDE;
#pragma unroll
            for (int rt = 0; rt < 4; ++rt)
#pragma unroll
                for (int r = 0; r < 4; ++r) {
                    const int k  = rt * 16 + lg * 4 + r;
                    const int i7 = k / 7, j7 = k - i7 * 7;
                    const int rr = hp + i7 - 3, cc = wp + j7 - 3;
                    const bool valid = (k < KK) & (rr >= 0) & (rr < WIDE) &
                                       (cc >= 0) & (cc < WIDE);
                    kw_lds[k * 64 + pxc] = valid ? (acc[ct][rt][r] + bias[rt][r]) : 0.f;
                }
        }
    }
    __syncthreads();

    // ---- Phase 2: involution, 4 px x 4 ch per thread ----
    {
        const int pg   = tid & 15;
        const int cq   = tid >> 4;
        const int hw4  = tile * 64 + pg * 4;         // 4-aligned flat pixel base
        const int hrow = hw4 / WIDE;
        const int hcol = hw4 - hrow * WIDE;          // 4-aligned (56 % 4 == 0)

        const float* bp[4];
#pragma unroll
        for (int c = 0; c < 4; ++c)
            bp[c] = x + ((size_t)b * C_IN + g * GC + cq * 4 + c) * HW;

        float acc2[4][4];   // [ch][px]
#pragma unroll
        for (int c = 0; c < 4; ++c)
#pragma unroll
            for (int p = 0; p < 4; ++p) acc2[c][p] = 0.f;

#pragma unroll
        for (int i = 0; i < 7; ++i) {
            const int rc    = min(max(hrow + i - 3, 0), WIDE - 1);  // v_med3
            const int basef = rc * WIDE + hcol;
            const int i0 = max(basef - 4, 0);
            const int i2 = min(basef + 4, HW - 4);

            float win[4][12];
#pragma unroll
            for (int c = 0; c < 4; ++c) {
                const f32x4 A0 = *(const f32x4*)(bp[c] + i0);
                const f32x4 A1 = *(const f32x4*)(bp[c] + basef);
                const f32x4 A2 = *(const f32x4*)(bp[c] + i2);
#pragma unroll
                for (int e = 0; e < 4; ++e) {
                    win[c][e]     = A0[e];
                    win[c][e + 4] = A1[e];
                    win[c][e + 8] = A2[e];
                }
            }
#pragma unroll
            for (int jj = 0; jj < 7; ++jj) {
                const f32x4 kw4 = *(const f32x4*)&kw_lds[(i * 7 + jj) * 64 + pg * 4];
#pragma unroll
                for (int c = 0; c < 4; ++c)
#pragma unroll
                    for (int p = 0; p < 4; ++p)
                        acc2[c][p] += kw4[p] * win[c][p + jj + 1];   // e = 4+(p+jj-3)
            }
        }

#pragma unroll
        for (int c = 0; c < 4; ++c) {
            f32x4 st;
#pragma unroll
            for (int p = 0; p < 4; ++p) st[p] = acc2[c][p];
            *(f32x4*)(out + ((size_t)b * C_IN + g * GC + cq * 4 + c) * HW + hw4) = st;
        }
    }
    __syncthreads();
    asm volatile("" ::: "memory");   // force full re-execution per rep
    }
}

extern "C" void kernel_launch(void* const* d_in, const int* in_sizes, int n_in,
                              void* d_out, int out_size, void* d_ws, size_t ws_size,
                              hipStream_t stream) {
    const float* x     = (const float*)d_in[0];
    const float* w1    = (const float*)d_in[1];
    const float* gamma = (const float*)d_in[2];
    const float* beta  = (const float*)d_in[3];
    const float* mean  = (const float*)d_in[4];
    const float* var   = (const float*)d_in[5];
    const float* w2    = (const float*)d_in[6];
    const float* b2    = (const float*)d_in[7];
    float* out = (float*)d_out;

    char* ws = (char*)d_ws;
    unsigned short* ybf   = (unsigned short*)(ws);             // 1,605,632 B
    unsigned short* wprep = (unsigned short*)(ws + 1605632);   //   131,072 B
    float*          b2pad = (float*)(ws + 1736704);            //     4,096 B
    float*          w1T   = (float*)(ws + 1740800);            //    65,536 B

    prep_kernel<<<dim3(256), dim3(256), 0, stream>>>(w1, w2, b2, w1T, wprep, b2pad);
    conv1_bn_relu<<<dim3(196, 4), dim3(256), 0, stream>>>(x, w1T, gamma, beta, mean, var, ybf);
    conv2_involution<<<dim3(49, 64), dim3(64), 0, stream>>>(x, ybf, wprep, b2pad, out);
}

// Round 9
// 63.380 us; speedup vs baseline: 5.3346x; 5.3346x over previous
//
#include <hip/hip_runtime.h>

// Involution fused kernels for MI355X (gfx950).
// x: (4,256,56,56) f32, w1: (64,256), bn(64), w2: (784,64), b2: (784)
// out: (4,256,56,56) f32
// ws: ybf16 [4][3136][64] | wprep bf16 [16][64][64] | b2pad f32 [16][64] | w1T f32 [256][64]

#define HW    3136
#define WIDE  56
#define C_IN  256
#define CR    64
#define GC    16
#define KK    49
#define BN_EPS 1e-5f

typedef __attribute__((ext_vector_type(8))) short short8;
typedef __attribute__((ext_vector_type(4))) float f32x4;
typedef __attribute__((ext_vector_type(2))) unsigned int u32x2;

__device__ __forceinline__ unsigned short f2bf(float f) {
    unsigned u = __float_as_uint(f);
    return (unsigned short)((u + 0x7FFFu + ((u >> 16) & 1u)) >> 16);   // RNE
}

// ---- Prep: w1T[c][o] f32; wprep[g][k][c] bf16 (k>=49 zero); b2pad[g][k] f32 ----
__global__ __launch_bounds__(256) void prep_kernel(
    const float* __restrict__ w1, const float* __restrict__ w2,
    const float* __restrict__ b2,
    float* __restrict__ w1T, unsigned short* __restrict__ wprep,
    float* __restrict__ b2pad)
{
    const int t = blockIdx.x * 256 + threadIdx.x;   // 0..65535
    if (t < 16384) {                                // w1T: c=t>>6, o=t&63
        const int c = t >> 6, o = t & 63;
        w1T[c * 64 + o] = w1[o * C_IN + c];
    }
    {                                               // wprep: g=t>>12, k=(t>>6)&63, c=t&63
        const int g = t >> 12, k = (t >> 6) & 63, c = t & 63;
        wprep[t] = (k < KK) ? f2bf(w2[(size_t)(g * KK + k) * CR + c]) : (unsigned short)0;
    }
    if (t < 1024) {                                 // b2pad
        const int g = t >> 6, k = t & 63;
        b2pad[t] = (k < KK) ? b2[g * KK + k] : 0.f;
    }
}

// ---- Kernel 1: y = relu(bn(w1 @ x)) -> bf16, layout [b][px][c] ----
// grid (196 px-tiles, 4 og-quads) x 256 thr (exact R5 known-good config).
__global__ __launch_bounds__(256) void conv1_bn_relu(
    const float* __restrict__ x, const float* __restrict__ w1T,
    const float* __restrict__ gamma, const float* __restrict__ beta,
    const float* __restrict__ mean, const float* __restrict__ var,
    unsigned short* __restrict__ ybf)
{
    const int t    = threadIdx.x;
    const int lane = t & 63;
    const int og   = __builtin_amdgcn_readfirstlane(blockIdx.y * 4 + (t >> 6)); // 0..15
    const int tile = blockIdx.x;          // 0..195
    const int b    = tile / 49;
    const int hw   = (tile - b * 49) * 64 + lane;

    const float* __restrict__ xb = x + (size_t)b * C_IN * HW + hw;

    float acc[4] = {0.f, 0.f, 0.f, 0.f};
#pragma unroll 8
    for (int c = 0; c < C_IN; ++c) {
        const float xv = xb[(size_t)c * HW];
        const f32x4 wv = *(const f32x4*)(w1T + c * 64 + og * 4);   // uniform -> s_load_dwordx4
#pragma unroll
        for (int u = 0; u < 4; ++u) acc[u] += wv[u] * xv;
    }

    unsigned short o4[4];
#pragma unroll
    for (int u = 0; u < 4; ++u) {
        const int o = og * 4 + u;
        const float sc = gamma[o] * rsqrtf(var[o] + BN_EPS);
        const float sh = beta[o] - mean[o] * sc;
        o4[u] = f2bf(fmaxf(acc[u] * sc + sh, 0.f));
    }
    u32x2 pack;
    pack.x = (unsigned)o4[0] | ((unsigned)o4[1] << 16);
    pack.y = (unsigned)o4[2] | ((unsigned)o4[3] << 16);
    *(u32x2*)(ybf + ((size_t)(b * HW + hw)) * 64 + og * 4) = pack;
}

// ---- Kernel 2: MFMA conv2 + vectorized involution. ----
// Block = (b, g, FOUR consecutive 64-px tiles), 256 thr, 50 KB LDS
//   -> 3 blocks/CU = 24 waves/CU (vs R5's ~8-10), VGPR kept low (~60).
// Phase 1 (R4's validated low-VGPR partition): wave q owns px-quadrant q;
//   loops over the 4 tiles, streaming Af/Bf 2-at-a-time, acc[4] f32x4 only.
//   Bias added, OOB taps zeroed -> kw_lds[t][k][px].
// Phase 2 (R5's validated per-thread code): wave tt owns tile tt; thread =
//   (pg -> 4 px, cq -> 4 ch); per row 3 aligned f32x4 x-loads, per tap 1
//   broadcast ds_read_b128 + 16 FMA. Garbage edge elems only hit kw==0.
__global__ __launch_bounds__(256) void conv2_involution(
    const float* __restrict__ x, const unsigned short* __restrict__ ybf,
    const unsigned short* __restrict__ wprep, const float* __restrict__ b2pad,
    float* __restrict__ out)
{
    __shared__ float kw_lds[4 * KK * 64];   // [tile][tap][px], 50176 B

    const int tid  = threadIdx.x;
    const int lane = tid & 63;
    const int q    = __builtin_amdgcn_readfirstlane(tid >> 6);  // wave 0..3
    const int l15  = lane & 15;
    const int lg   = lane >> 4;
    const int bx   = blockIdx.x;                 // 0..12 (4 tiles each)
    const int g    = blockIdx.y & 15;
    const int b    = blockIdx.y >> 4;

    // ---- Phase 1: kw = W2g @ y; wave q does px-quadrant q of each tile ----
#pragma unroll
    for (int t = 0; t < 4; ++t) {
        const int gt = bx * 4 + t;               // global 64-px tile id
        if (gt < 49) {
            const int px  = q * 16 + l15;        // 0..63 within tile
            const int hwp = gt * 64 + px;
            const unsigned short* yb = ybf + ((size_t)(b * HW + hwp)) * 64 + lg * 8;
            const short8 B0 = *(const short8*)(yb);
            const short8 B1 = *(const short8*)(yb + 32);

            f32x4 acc[4];
#pragma unroll
            for (int rt = 0; rt < 4; ++rt) {
                const unsigned short* ar = wprep + g * 4096 + (rt * 16 + l15) * 64 + lg * 8;
                const short8 A0 = *(const short8*)(ar);
                const short8 A1 = *(const short8*)(ar + 32);
                acc[rt] = (f32x4){0.f, 0.f, 0.f, 0.f};
                acc[rt] = __builtin_amdgcn_mfma_f32_16x16x32_bf16(A0, B0, acc[rt], 0, 0, 0);
                acc[rt] = __builtin_amdgcn_mfma_f32_16x16x32_bf16(A1, B1, acc[rt], 0, 0, 0);
            }

            const int hp = hwp / WIDE;
            const int wp = hwp - hp * WIDE;
#pragma unroll
            for (int rt = 0; rt < 4; ++rt)
#pragma unroll
                for (int r = 0; r < 4; ++r) {
                    const int k = rt * 16 + lg * 4 + r;
                    if (k < KK) {
                        const float val = acc[rt][r] + b2pad[g * 64 + k];
                        const int i7 = k / 7, j7 = k - i7 * 7;
                        const int rr = hp + i7 - 3, cc = wp + j7 - 3;
                        const bool valid = (rr >= 0) & (rr < WIDE) &
                                           (cc >= 0) & (cc < WIDE);
                        kw_lds[t * (KK * 64) + k * 64 + px] = valid ? val : 0.f;
                    }
                }
        }
    }
    __syncthreads();

    // ---- Phase 2: involution; wave tt owns tile tt; 4 px x 4 ch / thread ----
    const int tt = q;                            // wave id = tile slot
    const int gt = bx * 4 + tt;
    if (gt < 49) {
        const int pg   = tid & 15;
        const int cq   = (tid >> 4) & 3;
        const int hw4  = gt * 64 + pg * 4;       // 4-aligned flat pixel base
        const int hrow = hw4 / WIDE;
        const int hcol = hw4 - hrow * WIDE;      // 4-aligned (56 % 4 == 0)

        const float* bp[4];
#pragma unroll
        for (int c = 0; c < 4; ++c)
            bp[c] = x + ((size_t)b * C_IN + g * GC + cq * 4 + c) * HW;

        const float* __restrict__ kwb = kw_lds + tt * (KK * 64) + pg * 4;

        float acc2[4][4];   // [ch][px]
#pragma unroll
        for (int c = 0; c < 4; ++c)
#pragma unroll
            for (int p = 0; p < 4; ++p) acc2[c][p] = 0.f;

#pragma unroll
        for (int i = 0; i < 7; ++i) {
            const int rc    = min(max(hrow + i - 3, 0), WIDE - 1);  // v_med3
            const int basef = rc * WIDE + hcol;
            const int i0 = max(basef - 4, 0);
            const int i2 = min(basef + 4, HW - 4);

            float win[4][12];
#pragma unroll
            for (int c = 0; c < 4; ++c) {
                const f32x4 A0 = *(const f32x4*)(bp[c] + i0);
                const f32x4 A1 = *(const f32x4*)(bp[c] + basef);
                const f32x4 A2 = *(const f32x4*)(bp[c] + i2);
#pragma unroll
                for (int e = 0; e < 4; ++e) {
                    win[c][e]     = A0[e];
                    win[c][e + 4] = A1[e];
                    win[c][e + 8] = A2[e];
                }
            }
#pragma unroll
            for (int jj = 0; jj < 7; ++jj) {
                const f32x4 kw4 = *(const f32x4*)&kwb[(i * 7 + jj) * 64];
#pragma unroll
                for (int c = 0; c < 4; ++c)
#pragma unroll
                    for (int p = 0; p < 4; ++p)
                        acc2[c][p] += kw4[p] * win[c][p + jj + 1];   // e = 4+(p+jj-3)
            }
        }

#pragma unroll
        for (int c = 0; c < 4; ++c) {
            f32x4 st;
#pragma unroll
            for (int p = 0; p < 4; ++p) st[p] = acc2[c][p];
            *(f32x4*)(out + ((size_t)b * C_IN + g * GC + cq * 4 + c) * HW + hw4) = st;
        }
    }
}

extern "C" void kernel_launch(void* const* d_in, const int* in_sizes, int n_in,
                              void* d_out, int out_size, void* d_ws, size_t ws_size,
                              hipStream_t stream) {
    const float* x     = (const float*)d_in[0];
    const float* w1    = (const float*)d_in[1];
    const float* gamma = (const float*)d_in[2];
    const float* beta  = (const float*)d_in[3];
    const float* mean  = (const float*)d_in[4];
    const float* var   = (const float*)d_in[5];
    const float* w2    = (const float*)d_in[6];
    const float* b2    = (const float*)d_in[7];
    float* out = (float*)d_out;

    char* ws = (char*)d_ws;
    unsigned short* ybf   = (unsigned short*)(ws);             // 1,605,632 B
    unsigned short* wprep = (unsigned short*)(ws + 1605632);   //   131,072 B
    float*          b2pad = (float*)(ws + 1736704);            //     4,096 B
    float*          w1T   = (float*)(ws + 1740800);            //    65,536 B

    prep_kernel<<<dim3(256), dim3(256), 0, stream>>>(w1, w2, b2, w1T, wprep, b2pad);
    conv1_bn_relu<<<dim3(196, 4), dim3(256), 0, stream>>>(x, w1T, gamma, beta, mean, var, ybf);
    // 13 x-blocks of 4 tiles (last partially filled), 64 = b*g
    conv2_involution<<<dim3(13, 64), dim3(256), 0, stream>>>(x, ybf, wprep, b2pad, out);
}

// Round 10
// 55.191 us; speedup vs baseline: 6.1262x; 1.1484x over previous
//
#include <hip/hip_runtime.h>

// Involution fused kernels for MI355X (gfx950).
// x: (4,256,56,56) f32, w1: (64,256), bn(64), w2: (784,64), b2: (784)
// out: (4,256,56,56) f32
// ws: ybf16 [4][3136][64] | wprep bf16 [16][64][64] | b2pad f32 [16][64] | w1T f32 [256][64]

#define HW    3136
#define WIDE  56
#define C_IN  256
#define CR    64
#define GC    16
#define KK    49
#define BN_EPS 1e-5f

typedef __attribute__((ext_vector_type(8))) short short8;
typedef __attribute__((ext_vector_type(4))) float f32x4;
typedef __attribute__((ext_vector_type(2))) unsigned int u32x2;

__device__ __forceinline__ unsigned short f2bf(float f) {
    unsigned u = __float_as_uint(f);
    return (unsigned short)((u + 0x7FFFu + ((u >> 16) & 1u)) >> 16);   // RNE
}

// ---- Prep: w1T[c][o] f32; wprep[g][k][c] bf16 (k>=49 zero); b2pad[g][k] f32 ----
__global__ __launch_bounds__(256) void prep_kernel(
    const float* __restrict__ w1, const float* __restrict__ w2,
    const float* __restrict__ b2,
    float* __restrict__ w1T, unsigned short* __restrict__ wprep,
    float* __restrict__ b2pad)
{
    const int t = blockIdx.x * 256 + threadIdx.x;   // 0..65535
    if (t < 16384) {                                // w1T: c=t>>6, o=t&63
        const int c = t >> 6, o = t & 63;
        w1T[c * 64 + o] = w1[o * C_IN + c];
    }
    {                                               // wprep: g=t>>12, k=(t>>6)&63, c=t&63
        const int g = t >> 12, k = (t >> 6) & 63, c = t & 63;
        wprep[t] = (k < KK) ? f2bf(w2[(size_t)(g * KK + k) * CR + c]) : (unsigned short)0;
    }
    if (t < 1024) {                                 // b2pad
        const int g = t >> 6, k = t & 63;
        b2pad[t] = (k < KK) ? b2[g * KK + k] : 0.f;
    }
}

// ---- Kernel 1: y = relu(bn(w1 @ x)) -> bf16, layout [b][px][c] ----
// grid (196 px-tiles, 4 og-quads) x 256 thr (exact R5 known-good config).
__global__ __launch_bounds__(256) void conv1_bn_relu(
    const float* __restrict__ x, const float* __restrict__ w1T,
    const float* __restrict__ gamma, const float* __restrict__ beta,
    const float* __restrict__ mean, const float* __restrict__ var,
    unsigned short* __restrict__ ybf)
{
    const int t    = threadIdx.x;
    const int lane = t & 63;
    const int og   = __builtin_amdgcn_readfirstlane(blockIdx.y * 4 + (t >> 6)); // 0..15
    const int tile = blockIdx.x;          // 0..195
    const int b    = tile / 49;
    const int hw   = (tile - b * 49) * 64 + lane;

    const float* __restrict__ xb = x + (size_t)b * C_IN * HW + hw;

    float acc[4] = {0.f, 0.f, 0.f, 0.f};
#pragma unroll 8
    for (int c = 0; c < C_IN; ++c) {
        const float xv = xb[(size_t)c * HW];
        const f32x4 wv = *(const f32x4*)(w1T + c * 64 + og * 4);   // uniform -> s_load_dwordx4
#pragma unroll
        for (int u = 0; u < 4; ++u) acc[u] += wv[u] * xv;
    }

    unsigned short o4[4];
#pragma unroll
    for (int u = 0; u < 4; ++u) {
        const int o = og * 4 + u;
        const float sc = gamma[o] * rsqrtf(var[o] + BN_EPS);
        const float sh = beta[o] - mean[o] * sc;
        o4[u] = f2bf(fmaxf(acc[u] * sc + sh, 0.f));
    }
    u32x2 pack;
    pack.x = (unsigned)o4[0] | ((unsigned)o4[1] << 16);
    pack.y = (unsigned)o4[2] | ((unsigned)o4[3] << 16);
    *(u32x2*)(ybf + ((size_t)(b * HW + hw)) * 64 + og * 4) = pack;
}

// ---- Kernel 2: MFMA conv2 + vectorized involution. 2 waves / block. ----
// Block = (b, g, 64-px tile), 128 threads, 12.8 KB LDS
//   -> 12 blocks/CU (LDS cap) = 24 waves/CU target; per-thread footprint
//   deliberately SMALL (phase 1 streams A-frags + writes each f32x4 acc
//   immediately; phase 2 holds 6 in-flight f32x4).
// Phase 1: wave w does px-quadrants {w, w+2}; 8 MFMA each; bias added,
//   OOB taps zeroed -> kw_lds[k][px].
// Phase 2: thread = (pg = tid&15 -> 4 px, cp = tid>>4 -> 2 ch). Per row:
//   2ch x 3 aligned f32x4 x-loads; per tap: 1 broadcast ds_read_b128 +
//   8 FMA. Garbage edge elements only multiply kw==0.
__global__ __launch_bounds__(128) void conv2_involution(
    const float* __restrict__ x, const unsigned short* __restrict__ ybf,
    const unsigned short* __restrict__ wprep, const float* __restrict__ b2pad,
    float* __restrict__ out)
{
    __shared__ float kw_lds[50 * 64];   // [tap][px], 12.8 KB

    const int tid  = threadIdx.x;       // 0..127
    const int lane = tid & 63;
    const int wv   = __builtin_amdgcn_readfirstlane(tid >> 6);  // wave 0..1
    const int l15  = lane & 15;
    const int lg   = lane >> 4;
    const int tile = blockIdx.x;                 // 0..48
    const int g    = blockIdx.y & 15;
    const int b    = blockIdx.y >> 4;

    // ---- Phase 1: kw = W2g @ y; wave wv does quadrants {wv, wv+2} ----
#pragma unroll
    for (int cti = 0; cti < 2; ++cti) {
        const int ct  = wv + cti * 2;
        const int px  = ct * 16 + l15;
        const int hwp = tile * 64 + px;
        const unsigned short* yb = ybf + ((size_t)(b * HW + hwp)) * 64 + lg * 8;
        const short8 B0 = *(const short8*)(yb);
        const short8 B1 = *(const short8*)(yb + 32);
        const int hp = hwp / WIDE;
        const int wp = hwp - hp * WIDE;

#pragma unroll
        for (int rt = 0; rt < 4; ++rt) {
            const unsigned short* ar = wprep + g * 4096 + (rt * 16 + l15) * 64 + lg * 8;
            const short8 A0 = *(const short8*)(ar);
            const short8 A1 = *(const short8*)(ar + 32);
            f32x4 acc = (f32x4){0.f, 0.f, 0.f, 0.f};
            acc = __builtin_amdgcn_mfma_f32_16x16x32_bf16(A0, B0, acc, 0, 0, 0);
            acc = __builtin_amdgcn_mfma_f32_16x16x32_bf16(A1, B1, acc, 0, 0, 0);
#pragma unroll
            for (int r = 0; r < 4; ++r) {
                const int k = rt * 16 + lg * 4 + r;
                if (k < KK) {
                    const float val = acc[r] + b2pad[g * 64 + k];
                    const int i7 = k / 7, j7 = k - i7 * 7;
                    const int rr = hp + i7 - 3, cc = wp + j7 - 3;
                    const bool valid = (rr >= 0) & (rr < WIDE) &
                                       (cc >= 0) & (cc < WIDE);
                    kw_lds[k * 64 + px] = valid ? val : 0.f;
                }
            }
        }
    }
    __syncthreads();

    // ---- Phase 2: involution, 4 px x 2 ch per thread ----
    const int pg   = tid & 15;
    const int cp   = tid >> 4;                   // 0..7 -> channels cp*2, cp*2+1
    const int hw4  = tile * 64 + pg * 4;         // 4-aligned flat pixel base
    const int hrow = hw4 / WIDE;
    const int hcol = hw4 - hrow * WIDE;          // 4-aligned (56 % 4 == 0)

    const float* __restrict__ bp0 = x + ((size_t)b * C_IN + g * GC + cp * 2) * HW;
    const float* __restrict__ bp1 = bp0 + HW;

    float acc2[2][4];   // [ch][px]
#pragma unroll
    for (int c = 0; c < 2; ++c)
#pragma unroll
        for (int p = 0; p < 4; ++p) acc2[c][p] = 0.f;

#pragma unroll
    for (int i = 0; i < 7; ++i) {
        const int rc    = min(max(hrow + i - 3, 0), WIDE - 1);  // v_med3
        const int basef = rc * WIDE + hcol;
        const int i0 = max(basef - 4, 0);
        const int i2 = min(basef + 4, HW - 4);

        float win[2][12];
        {
            const f32x4 A0 = *(const f32x4*)(bp0 + i0);
            const f32x4 A1 = *(const f32x4*)(bp0 + basef);
            const f32x4 A2 = *(const f32x4*)(bp0 + i2);
            const f32x4 B0 = *(const f32x4*)(bp1 + i0);
            const f32x4 B1 = *(const f32x4*)(bp1 + basef);
            const f32x4 B2 = *(const f32x4*)(bp1 + i2);
#pragma unroll
            for (int e = 0; e < 4; ++e) {
                win[0][e]     = A0[e];
                win[0][e + 4] = A1[e];
                win[0][e + 8] = A2[e];
                win[1][e]     = B0[e];
                win[1][e + 4] = B1[e];
                win[1][e + 8] = B2[e];
            }
        }
#pragma unroll
        for (int jj = 0; jj < 7; ++jj) {
            const f32x4 kw4 = *(const f32x4*)&kw_lds[(i * 7 + jj) * 64 + pg * 4];
#pragma unroll
            for (int c = 0; c < 2; ++c)
#pragma unroll
                for (int p = 0; p < 4; ++p)
                    acc2[c][p] += kw4[p] * win[c][p + jj + 1];   // e = 4+(p+jj-3)
        }
    }

    f32x4 st0, st1;
#pragma unroll
    for (int p = 0; p < 4; ++p) { st0[p] = acc2[0][p]; st1[p] = acc2[1][p]; }
    float* __restrict__ ob = out + ((size_t)b * C_IN + g * GC + cp * 2) * HW + hw4;
    *(f32x4*)(ob)      = st0;
    *(f32x4*)(ob + HW) = st1;
}

extern "C" void kernel_launch(void* const* d_in, const int* in_sizes, int n_in,
                              void* d_out, int out_size, void* d_ws, size_t ws_size,
                              hipStream_t stream) {
    const float* x     = (const float*)d_in[0];
    const float* w1    = (const float*)d_in[1];
    const float* gamma = (const float*)d_in[2];
    const float* beta  = (const float*)d_in[3];
    const float* mean  = (const float*)d_in[4];
    const float* var   = (const float*)d_in[5];
    const float* w2    = (const float*)d_in[6];
    const float* b2    = (const float*)d_in[7];
    float* out = (float*)d_out;

    char* ws = (char*)d_ws;
    unsigned short* ybf   = (unsigned short*)(ws);             // 1,605,632 B
    unsigned short* wprep = (unsigned short*)(ws + 1605632);   //   131,072 B
    float*          b2pad = (float*)(ws + 1736704);            //     4,096 B
    float*          w1T   = (float*)(ws + 1740800);            //    65,536 B

    prep_kernel<<<dim3(256), dim3(256), 0, stream>>>(w1, w2, b2, w1T, wprep, b2pad);
    conv1_bn_relu<<<dim3(196, 4), dim3(256), 0, stream>>>(x, w1T, gamma, beta, mean, var, ybf);
    conv2_involution<<<dim3(49, 64), dim3(128), 0, stream>>>(x, ybf, wprep, b2pad, out);
}

// Round 11
// 40.832 us; speedup vs baseline: 8.2804x; 1.3516x over previous
//
#include <hip/hip_runtime.h>

// Involution fused kernels for MI355X (gfx950).
// x: (4,256,56,56) f32, w1: (64,256), bn(64), w2: (784,64), b2: (784)
// out: (4,256,56,56) f32
// ws: ybf16 [4][3136][64] | wprep bf16 [16][64][64] | b2pad f32 [16][64] | w1bf bf16 [64][256]

#define HW    3136
#define WIDE  56
#define C_IN  256
#define CR    64
#define GC    16
#define KK    49
#define BN_EPS 1e-5f

typedef __attribute__((ext_vector_type(8))) short short8;
typedef __attribute__((ext_vector_type(4))) float f32x4;
typedef __attribute__((ext_vector_type(2))) unsigned int u32x2;

__device__ __forceinline__ unsigned short f2bf(float f) {
    unsigned u = __float_as_uint(f);
    return (unsigned short)((u + 0x7FFFu + ((u >> 16) & 1u)) >> 16);   // RNE
}

// ---- Prep: w1bf[o][c] bf16; wprep[g][k][c] bf16 (k>=49 zero); b2pad[g][k] f32 ----
__global__ __launch_bounds__(256) void prep_kernel(
    const float* __restrict__ w1, const float* __restrict__ w2,
    const float* __restrict__ b2,
    unsigned short* __restrict__ w1bf, unsigned short* __restrict__ wprep,
    float* __restrict__ b2pad)
{
    const int t = blockIdx.x * 256 + threadIdx.x;   // 0..65535
    if (t < 16384) {                                // w1bf: same [o][c] layout
        w1bf[t] = f2bf(w1[t]);
    }
    {                                               // wprep: g=t>>12, k=(t>>6)&63, c=t&63
        const int g = t >> 12, k = (t >> 6) & 63, c = t & 63;
        wprep[t] = (k < KK) ? f2bf(w2[(size_t)(g * KK + k) * CR + c]) : (unsigned short)0;
    }
    if (t < 1024) {                                 // b2pad
        const int g = t >> 6, k = t & 63;
        b2pad[t] = (k < KK) ? b2[g * KK + k] : 0.f;
    }
}

// LDS xs[px][c] bf16, XOR-swizzled: byte = (px*512 + c*2) ^ ((px&7)<<4).
// Write side (16B chunks of 8 c's) and read side (MFMA B-frags, 16B) use
// the same involution -> consistent; spreads the px-varying accesses over
// all 32 banks (pure-bandwidth, no conflict overhead).
__device__ __forceinline__ int xs_byte(int px, int c) {
    return ((px << 9) + (c << 1)) ^ ((px & 7) << 4);
}

// ---- Kernel 1: y = relu(bn(w1 @ x)) -> bf16 [b][px][c], via MFMA ----
// 196 blocks (b, 64-px tile) x 256 thr (4 waves).
// Stage: thread (q,lane): px=lane, c in [q*64, q*64+64): 64 coalesced dword
//   loads, f2bf, 8x ds_write_b128 (swizzled).
// Compute: wave q owns px-quadrant q (16 px): 8 K-steps x {1 ds_read_b128
//   B-frag + 4 global A-frags (w1bf, L1-hot) + 4 MFMA} -> acc[4] f32x4.
// Epilogue: BN+ReLU per o (f32x4 param loads), f2bf, 8B stores to ybf.
__global__ __launch_bounds__(256) void conv1_bn_relu(
    const float* __restrict__ x, const unsigned short* __restrict__ w1bf,
    const float* __restrict__ gamma, const float* __restrict__ beta,
    const float* __restrict__ mean, const float* __restrict__ var,
    unsigned short* __restrict__ ybf)
{
    __shared__ unsigned short xs[64 * 256];   // 32 KB

    const int t    = threadIdx.x;
    const int lane = t & 63;
    const int q    = __builtin_amdgcn_readfirstlane(t >> 6);  // wave 0..3
    const int tile = blockIdx.x;              // 0..195
    const int b    = tile / 49;
    const int hw0  = (tile - b * 49) * 64;

    // ---- stage x[b][c][hw0+lane] -> xs[lane][c] ----
    {
        const int px = lane;
        const int cb = q * 64;
        const float* __restrict__ xb = x + ((size_t)b * C_IN + cb) * HW + hw0 + px;
#pragma unroll
        for (int i = 0; i < 8; ++i) {
            short8 pk;
#pragma unroll
            for (int j = 0; j < 8; ++j)
                pk[j] = (short)f2bf(xb[(size_t)(i * 8 + j) * HW]);
            *(short8*)((char*)xs + xs_byte(px, cb + i * 8)) = pk;
        }
    }
    __syncthreads();

    // ---- MFMA: y[o][px] for px-quadrant q ----
    const int l15 = lane & 15;
    const int lg  = lane >> 4;
    const int px  = q * 16 + l15;

    f32x4 acc[4];
#pragma unroll
    for (int mt = 0; mt < 4; ++mt) acc[mt] = (f32x4){0.f, 0.f, 0.f, 0.f};

#pragma unroll
    for (int kk = 0; kk < 8; ++kk) {
        const short8 Bf = *(const short8*)((const char*)xs + xs_byte(px, kk * 32 + lg * 8));
#pragma unroll
        for (int mt = 0; mt < 4; ++mt) {
            const short8 Af = *(const short8*)(w1bf + (mt * 16 + l15) * C_IN + kk * 32 + lg * 8);
            acc[mt] = __builtin_amdgcn_mfma_f32_16x16x32_bf16(Af, Bf, acc[mt], 0, 0, 0);
        }
    }

    // ---- BN + ReLU + pack; D: col=l15 -> px, row=lg*4+r -> o ----
#pragma unroll
    for (int mt = 0; mt < 4; ++mt) {
        const int o0 = mt * 16 + lg * 4;
        const f32x4 ga = *(const f32x4*)(gamma + o0);
        const f32x4 be = *(const f32x4*)(beta + o0);
        const f32x4 mn = *(const f32x4*)(mean + o0);
        const f32x4 va = *(const f32x4*)(var + o0);
        unsigned short o4[4];
#pragma unroll
        for (int r = 0; r < 4; ++r) {
            const float sc = ga[r] * rsqrtf(va[r] + BN_EPS);
            const float sh = be[r] - mn[r] * sc;
            o4[r] = f2bf(fmaxf(acc[mt][r] * sc + sh, 0.f));
        }
        u32x2 pk;
        pk.x = (unsigned)o4[0] | ((unsigned)o4[1] << 16);
        pk.y = (unsigned)o4[2] | ((unsigned)o4[3] << 16);
        *(u32x2*)(ybf + ((size_t)(b * HW + hw0 + px)) * 64 + o0) = pk;
    }
}

// ---- Kernel 2: MFMA conv2 + vectorized involution (EXACT R5 code). ----
__global__ __launch_bounds__(64) void conv2_involution(
    const float* __restrict__ x, const unsigned short* __restrict__ ybf,
    const unsigned short* __restrict__ wprep, const float* __restrict__ b2pad,
    float* __restrict__ out)
{
    __shared__ float kw_lds[64 * 64];   // [tap][px], 16 KB

    const int tid  = threadIdx.x;
    const int l15  = tid & 15;
    const int lg   = tid >> 4;
    const int tile = blockIdx.x;                 // 0..48
    const int g    = blockIdx.y & 15;
    const int b    = blockIdx.y >> 4;

    // ---- Phase 1: kw = W2g @ y  (per-pixel 64-tap kernels) ----
    {
        short8 Bf[4][2], Af[4][2];
#pragma unroll
        for (int ct = 0; ct < 4; ++ct) {
            const int hwp = tile * 64 + ct * 16 + l15;
            const unsigned short* yb = ybf + ((size_t)(b * HW + hwp)) * 64 + lg * 8;
            Bf[ct][0] = *(const short8*)(yb);
            Bf[ct][1] = *(const short8*)(yb + 32);
        }
#pragma unroll
        for (int rt = 0; rt < 4; ++rt) {
            const unsigned short* ar = wprep + g * 4096 + (rt * 16 + l15) * 64 + lg * 8;
            Af[rt][0] = *(const short8*)(ar);
            Af[rt][1] = *(const short8*)(ar + 32);
        }
        f32x4 acc[4][4];
#pragma unroll
        for (int ct = 0; ct < 4; ++ct)
#pragma unroll
            for (int rt = 0; rt < 4; ++rt) {
                acc[ct][rt] = (f32x4){0.f, 0.f, 0.f, 0.f};
                acc[ct][rt] = __builtin_amdgcn_mfma_f32_16x16x32_bf16(Af[rt][0], Bf[ct][0], acc[ct][rt], 0, 0, 0);
                acc[ct][rt] = __builtin_amdgcn_mfma_f32_16x16x32_bf16(Af[rt][1], Bf[ct][1], acc[ct][rt], 0, 0, 0);
            }

        float bias[4][4];
#pragma unroll
        for (int rt = 0; rt < 4; ++rt)
#pragma unroll
            for (int r = 0; r < 4; ++r)
                bias[rt][r] = b2pad[g * 64 + rt * 16 + lg * 4 + r];

#pragma unroll
        for (int ct = 0; ct < 4; ++ct) {
            const int pxc = ct * 16 + l15;
            const int hwp = tile * 64 + pxc;
            const int hp  = hwp / WIDE;
            const int wp  = hwp - hp * WIDE;
#pragma unroll
            for (int rt = 0; rt < 4; ++rt)
#pragma unroll
                for (int r = 0; r < 4; ++r) {
                    const int k  = rt * 16 + lg * 4 + r;
                    const int i7 = k / 7, j7 = k - i7 * 7;
                    const int rr = hp + i7 - 3, cc = wp + j7 - 3;
                    const bool valid = (k < KK) & (rr >= 0) & (rr < WIDE) &
                                       (cc >= 0) & (cc < WIDE);
                    kw_lds[k * 64 + pxc] = valid ? (acc[ct][rt][r] + bias[rt][r]) : 0.f;
                }
        }
    }
    __syncthreads();

    // ---- Phase 2: involution, 4 px x 4 ch per thread ----
    const int pg   = tid & 15;
    const int cq   = tid >> 4;
    const int hw4  = tile * 64 + pg * 4;         // 4-aligned flat pixel base
    const int hrow = hw4 / WIDE;
    const int hcol = hw4 - hrow * WIDE;          // 4-aligned (56 % 4 == 0)

    const float* bp[4];
#pragma unroll
    for (int c = 0; c < 4; ++c)
        bp[c] = x + ((size_t)b * C_IN + g * GC + cq * 4 + c) * HW;

    float acc2[4][4];   // [ch][px]
#pragma unroll
    for (int c = 0; c < 4; ++c)
#pragma unroll
        for (int p = 0; p < 4; ++p) acc2[c][p] = 0.f;

#pragma unroll
    for (int i = 0; i < 7; ++i) {
        const int rc    = min(max(hrow + i - 3, 0), WIDE - 1);  // v_med3
        const int basef = rc * WIDE + hcol;
        const int i0 = max(basef - 4, 0);
        const int i2 = min(basef + 4, HW - 4);

        float win[4][12];
#pragma unroll
        for (int c = 0; c < 4; ++c) {
            const f32x4 A0 = *(const f32x4*)(bp[c] + i0);
            const f32x4 A1 = *(const f32x4*)(bp[c] + basef);
            const f32x4 A2 = *(const f32x4*)(bp[c] + i2);
#pragma unroll
            for (int e = 0; e < 4; ++e) {
                win[c][e]     = A0[e];
                win[c][e + 4] = A1[e];
                win[c][e + 8] = A2[e];
            }
        }
#pragma unroll
        for (int jj = 0; jj < 7; ++jj) {
            const f32x4 kw4 = *(const f32x4*)&kw_lds[(i * 7 + jj) * 64 + pg * 4];
#pragma unroll
            for (int c = 0; c < 4; ++c)
#pragma unroll
                for (int p = 0; p < 4; ++p)
                    acc2[c][p] += kw4[p] * win[c][p + jj + 1];   // e = 4+(p+jj-3)
        }
    }

#pragma unroll
    for (int c = 0; c < 4; ++c) {
        f32x4 st;
#pragma unroll
        for (int p = 0; p < 4; ++p) st[p] = acc2[c][p];
        *(f32x4*)(out + ((size_t)b * C_IN + g * GC + cq * 4 + c) * HW + hw4) = st;
    }
}

extern "C" void kernel_launch(void* const* d_in, const int* in_sizes, int n_in,
                              void* d_out, int out_size, void* d_ws, size_t ws_size,
                              hipStream_t stream) {
    const float* x     = (const float*)d_in[0];
    const float* w1    = (const float*)d_in[1];
    const float* gamma = (const float*)d_in[2];
    const float* beta  = (const float*)d_in[3];
    const float* mean  = (const float*)d_in[4];
    const float* var   = (const float*)d_in[5];
    const float* w2    = (const float*)d_in[6];
    const float* b2    = (const float*)d_in[7];
    float* out = (float*)d_out;

    char* ws = (char*)d_ws;
    unsigned short* ybf   = (unsigned short*)(ws);             // 1,605,632 B
    unsigned short* wprep = (unsigned short*)(ws + 1605632);   //   131,072 B
    float*          b2pad = (float*)(ws + 1736704);            //     4,096 B
    unsigned short* w1bf  = (unsigned short*)(ws + 1740800);   //    32,768 B

    prep_kernel<<<dim3(256), dim3(256), 0, stream>>>(w1, w2, b2, w1bf, wprep, b2pad);
    conv1_bn_relu<<<dim3(196), dim3(256), 0, stream>>>(x, w1bf, gamma, beta, mean, var, ybf);
    conv2_involution<<<dim3(49, 64), dim3(64), 0, stream>>>(x, ybf, wprep, b2pad, out);
}